// Round 8
// baseline (11.518 us; speedup 1.0000x reference)
//
#include <hip/hip_runtime.h>
#include <stdint.h>

#define OUTHW 511
#define IMGW 512

// ============ compile-time numpy RandomState(42) replication ============
struct COps { int n; int kind[64]; int wa[64]; int wb[64]; int widx[64]; };

struct CMT {
    uint32_t mt[624]; int mti;
    constexpr CMT(uint32_t s) : mt{}, mti(624) {
        mt[0] = s;
        for (int i = 1; i < 624; ++i)
            mt[i] = 1812433253u * (mt[i - 1] ^ (mt[i - 1] >> 30)) + (uint32_t)i;
    }
    constexpr uint32_t next32() {
        if (mti >= 624) {
            for (int i = 0; i < 624; ++i) {
                uint32_t y = (mt[i] & 0x80000000u) | (mt[(i + 1) % 624] & 0x7fffffffu);
                mt[i] = mt[(i + 397) % 624] ^ (y >> 1) ^ ((y & 1u) ? 0x9908b0dfu : 0u);
            }
            mti = 0;
        }
        uint32_t y = mt[mti++];
        y ^= y >> 11; y ^= (y << 7) & 0x9d2c5680u; y ^= (y << 15) & 0xefc60000u; y ^= y >> 18;
        return y;
    }
    constexpr double rand_double() {  // random_sample(): 2 draws
        uint32_t a = next32() >> 5, b = next32() >> 6;
        return (a * 67108864.0 + b) / 9007199254740992.0;
    }
    constexpr uint32_t interval(uint32_t mx) {  // legacy masked randint
        if (mx == 0) return 0;
        uint32_t mask = mx;
        mask |= mask >> 1; mask |= mask >> 2; mask |= mask >> 4;
        mask |= mask >> 8; mask |= mask >> 16;
        uint32_t v = next32() & mask;
        while (v > mx) v = next32() & mask;
        return v;
    }
};

constexpr COps build_ops_ce() {
    CMT mt(42u); COps P{}; P.n = 0;
    for (int l = 0; l < 2; ++l) {
        int i = 0;
        while (i < 4 && P.n < 64) {
            if (mt.rand_double() > 0.3) {
                int g = (int)mt.interval(2);  // randint(3)
                int w = (int)mt.interval(3);  // randint(4)
                P.kind[P.n] = g; P.wa[P.n] = w; P.wb[P.n] = 0; P.widx[P.n] = l * 4 + i;
                ++P.n; ++i;
            } else {  // choice(4,2,replace=False) == permutation(4)[:2]
                int arr[4] = {0, 1, 2, 3};
                for (int ii = 3; ii >= 1; --ii) {
                    int j = (int)mt.interval((uint32_t)ii);
                    int t = arr[ii]; arr[ii] = arr[j]; arr[j] = t;
                }
                P.kind[P.n] = 3; P.wa[P.n] = arr[0]; P.wb[P.n] = arr[1]; P.widx[P.n] = -1;
                ++P.n;
            }
        }
    }
    return P;
}
constexpr COps OPS = build_ops_ce();

// ===== compile-time Heisenberg support: which W_j[t] can be nonzero =====
struct Tabs {
    bool u[81];        // union support over j
    bool mj[4][81];    // per-output support
    int nu;            // |union|
    int tlist[81];     // compacted union t list
    int zm[81], xm[81];// stage-2 state-index masks per t
};

constexpr Tabs build_tabs() {
    Tabs T{};
    for (int j = 0; j < 4; ++j) {
        bool cur[256] = {};
        cur[1 << (4 + j)] = true;  // Z_j
        for (int o = OPS.n - 1; o >= 0; --o) {
            bool nxt[256] = {};
            for (int c = 0; c < 256; ++c) if (cur[c]) {
                if (OPS.kind[o] == 3) {  // CNOT: x_t ^= x_c ; z_c ^= z_t
                    int cc = OPS.wa[o], tt = OPS.wb[o], nc = c;
                    if (c & (1 << cc))       nc ^= (1 << tt);
                    if (c & (1 << (4 + tt))) nc ^= (1 << (4 + cc));
                    nxt[nc] = true;
                } else {
                    int w = OPS.wa[o];
                    int xw = (c >> w) & 1, zw = (c >> (4 + w)) & 1;
                    bool anti = false; int pm = 0;
                    if (OPS.kind[o] == 0)      { anti = zw != 0;        pm = 1 << w; }                    // RX
                    else if (OPS.kind[o] == 1) { anti = (xw ^ zw) != 0; pm = (1 << w) | (1 << (4 + w)); } // RY
                    else                       { anti = xw != 0;        pm = 1 << (4 + w); }              // RZ
                    nxt[c] = true;
                    if (anti) nxt[c ^ pm] = true;
                }
            }
            for (int c = 0; c < 256; ++c) cur[c] = nxt[c];
        }
        for (int c = 0; c < 256; ++c) if (cur[c]) {
            bool hasY = false; int t = 0;
            for (int k = 0; k < 4; ++k) {
                int xk = (c >> k) & 1, zk = (c >> (4 + k)) & 1;
                if (xk && zk) hasY = true;            // <Y> = 0 for real product state
                t = t * 3 + (zk ? 1 : (xk ? 2 : 0));  // qubit k at place 3^(3-k)
            }
            if (!hasY) { T.mj[j][t] = true; T.u[t] = true; }
        }
    }
    T.nu = 0;
    for (int t = 0; t < 81; ++t) {
        int dd[4] = {t / 27, (t / 9) % 3, (t / 3) % 3, t % 3};
        int zm = 0, xm = 0;
        for (int k = 0; k < 4; ++k) {
            int p = 3 - k;
            if (dd[k] == 1) zm |= 1 << p;
            else if (dd[k] == 2) xm |= 1 << p;
        }
        T.zm[t] = zm; T.xm[t] = xm;
        if (T.u[t]) T.tlist[T.nu++] = t;
    }
    return T;
}
constexpr Tabs TB = build_tabs();
constexpr int NU = TB.nu;

// Fused kernel, 2 output rows per thread. Phase order chosen for latency
// hiding: (0) issue 18 global loads -> (1) register U-build by 16 threads
// (zero intermediate barriers; load latency hides under it) -> stage 2/3 in
// LDS -> (2) trig + monomials -> (3) contraction + stores.
__global__ void __launch_bounds__(256) quanv_fused(const float* __restrict__ x,
                                                   const float* __restrict__ wts,
                                                   float* __restrict__ out) {
    __shared__ float Ur[256];     // [b*16+n] = Re U[n][b]
    __shared__ float Ui[256];
    __shared__ float S[81 * 16];  // stage-2 partials per (t,n)
    __shared__ __align__(16) float Wl[81][4];  // [t][j], zero where masked

    const int tid = threadIdx.x;
    const int j = blockIdx.x * blockDim.x + tid;
    const int i0 = blockIdx.y * 2;             // output rows i0, i0+1
    const int jj = (j < OUTHW) ? j : (OUTHW - 1);     // clamp OOB lanes' loads
    const int r2 = (i0 + 2 <= 511) ? (i0 + 2) : 511;  // clamp bottom input row

    // ---- Phase 0: issue all pixel loads (first use is after stage 3) ----
    float ld[3][6];  // [ch][row*2+col], compile-time indexed -> VGPRs
#pragma unroll
    for (int c = 0; c < 3; ++c) {
        const float* xc = x + (size_t)c * (IMGW * IMGW);
        ld[c][0] = xc[i0 * IMGW + jj];       ld[c][1] = xc[i0 * IMGW + jj + 1];
        ld[c][2] = xc[(i0 + 1) * IMGW + jj]; ld[c][3] = xc[(i0 + 1) * IMGW + jj + 1];
        ld[c][4] = xc[r2 * IMGW + jj];       ld[c][5] = xc[r2 * IMGW + jj + 1];
    }

    const float INV4PI = 0.07957747154594767f;  // 1/(4*pi)

    // ---- Phase 1: register U-build, thread b<16 owns column b ----
    if (tid < 16) {
        float ur[16], ui[16];
#pragma unroll
        for (int n = 0; n < 16; ++n) { ur[n] = (n == tid) ? 1.f : 0.f; ui[n] = 0.f; }
#pragma unroll
        for (int o = 0; o < OPS.n; ++o) {
            if (OPS.kind[o] == 3) {  // CNOT: swap rows n <-> n|1<<pt where pc set
                const int pc = 3 - OPS.wa[o], pt = 3 - OPS.wb[o];
#pragma unroll
                for (int n = 0; n < 16; ++n) {
                    if ((n & (1 << pc)) && !(n & (1 << pt))) {
                        const int n2 = n | (1 << pt);
                        float tr = ur[n]; ur[n] = ur[n2]; ur[n2] = tr;
                        float ti = ui[n]; ui[n] = ui[n2]; ui[n2] = ti;
                    }
                }
            } else {  // rotation on state-index bit p (same expressions as before)
                const float th = wts[OPS.widx[o]];
                const float ch = __builtin_amdgcn_cosf(th * INV4PI);  // cos(th/2)
                const float sh = __builtin_amdgcn_sinf(th * INV4PI);  // sin(th/2)
                const int p = 3 - OPS.wa[o];
#pragma unroll
                for (int n0 = 0; n0 < 16; ++n0) {
                    if (n0 & (1 << p)) continue;
                    const int n1 = n0 | (1 << p);
                    const float a0r = ur[n0], a0i = ui[n0];
                    const float a1r = ur[n1], a1i = ui[n1];
                    float b0r, b0i, b1r, b1i;
                    if (OPS.kind[o] == 0) {        // RX
                        b0r = ch * a0r + sh * a1i;  b0i = ch * a0i - sh * a1r;
                        b1r = sh * a0i + ch * a1r;  b1i = -sh * a0r + ch * a1i;
                    } else if (OPS.kind[o] == 1) { // RY
                        b0r = ch * a0r - sh * a1r;  b0i = ch * a0i - sh * a1i;
                        b1r = sh * a0r + ch * a1r;  b1i = sh * a0i + ch * a1i;
                    } else {                       // RZ
                        b0r = ch * a0r + sh * a0i;  b0i = ch * a0i - sh * a0r;
                        b1r = ch * a1r - sh * a1i;  b1i = ch * a1i + sh * a1r;
                    }
                    ur[n0] = b0r; ui[n0] = b0i;
                    ur[n1] = b1r; ui[n1] = b1i;
                }
            }
        }
        // publish column to LDS
#pragma unroll
        for (int n = 0; n < 16; ++n) {
            Ur[tid * 16 + n] = ur[n];
            Ui[tid * 16 + n] = ui[n];
        }
    }
    __syncthreads();

    // Stage 2 (union-masked): S[t][n]
    for (int item = tid; item < NU * 16; item += 256) {
        const int t = TB.tlist[item >> 4], n = item & 15;
        const int zmask = TB.zm[t], xmask = TB.xm[t];
        float s = 0.f;
#pragma unroll
        for (int b2 = 0; b2 < 16; ++b2) {
            int bx = b2 ^ xmask;
            float sgn = (__popc(b2 & zmask) & 1) ? -1.f : 1.f;
            s += sgn * (Ur[b2 * 16 + n] * Ur[bx * 16 + n] +
                        Ui[b2 * 16 + n] * Ui[bx * 16 + n]);
        }
        S[t * 16 + n] = s;
    }
    __syncthreads();
    // Stage 3: Wl[t][jo] = (1/16) sum_n z_jo(n) S[t][n]  (0 where masked)
    for (int item = tid; item < 324; item += 256) {
        const int jo = item / 81, t = item % 81;
        float acc = 0.f;
        if (TB.mj[jo][t]) {
#pragma unroll
            for (int n = 0; n < 16; ++n) {
                float zj = ((n >> (3 - jo)) & 1) ? -1.f : 1.f;
                acc += zj * S[t * 16 + n];
            }
            acc *= 0.0625f;
        }
        Wl[t][jo] = acc;
    }
    __syncthreads();

    // ---- Phase 2: trig + monomials (loads' vmcnt waits land here) ----
    float mon1[81], mon2[81];
#pragma unroll
    for (int t = 0; t < 81; ++t) { mon1[t] = 0.f; mon2[t] = 0.f; }

#pragma unroll
    for (int c = 0; c < 3; ++c) {
        // sin(pi p) = v_sin(2pi*(p/2)): HW trig takes revolutions
        const float cA0 = __builtin_amdgcn_cosf(0.5f * ld[c][0]), sA0 = __builtin_amdgcn_sinf(0.5f * ld[c][0]);
        const float cA1 = __builtin_amdgcn_cosf(0.5f * ld[c][1]), sA1 = __builtin_amdgcn_sinf(0.5f * ld[c][1]);
        const float cB0 = __builtin_amdgcn_cosf(0.5f * ld[c][2]), sB0 = __builtin_amdgcn_sinf(0.5f * ld[c][2]);
        const float cB1 = __builtin_amdgcn_cosf(0.5f * ld[c][3]), sB1 = __builtin_amdgcn_sinf(0.5f * ld[c][3]);
        const float cC0 = __builtin_amdgcn_cosf(0.5f * ld[c][4]), sC0 = __builtin_amdgcn_sinf(0.5f * ld[c][4]);
        const float cC1 = __builtin_amdgcn_cosf(0.5f * ld[c][5]), sC1 = __builtin_amdgcn_sinf(0.5f * ld[c][5]);
        const float vA0[3] = {1.f, cA0, sA0}, vA1[3] = {1.f, cA1, sA1};
        const float vB0[3] = {1.f, cB0, sB0}, vB1[3] = {1.f, cB1, sB1};
        const float vC0[3] = {1.f, cC0, sC0}, vC1[3] = {1.f, cC1, sC1};
        float mA[9], mB[9], mC[9];
#pragma unroll
        for (int a = 0; a < 3; ++a)
#pragma unroll
            for (int b = 0; b < 3; ++b) {
                mA[a * 3 + b] = vA0[a] * vA1[b];
                mB[a * 3 + b] = vB0[a] * vB1[b];
                mC[a * 3 + b] = vC0[a] * vC1[b];
            }
#pragma unroll
        for (int a = 0; a < 9; ++a)
#pragma unroll
            for (int b = 0; b < 9; ++b)
                if (TB.u[a * 9 + b]) {  // constexpr-folded
                    mon1[a * 9 + b] = fmaf(mA[a], mB[b], mon1[a * 9 + b]);
                    mon2[a * 9 + b] = fmaf(mB[a], mC[b], mon2[a * 9 + b]);
                }
    }

    // ---- Phase 3: contraction + stores for both rows ----
    if (j >= OUTHW) return;
    float a0 = 0.f, a1 = 0.f, a2 = 0.f, a3 = 0.f;
    float b0 = 0.f, b1 = 0.f, b2 = 0.f, b3 = 0.f;
#pragma unroll
    for (int t = 0; t < 81; ++t) {
        if (!TB.u[t]) continue;  // constexpr-folded
        const float4 w = *reinterpret_cast<const float4*>(&Wl[t][0]);
        const float m1 = mon1[t], m2 = mon2[t];
        if (TB.mj[0][t]) { a0 = fmaf(w.x, m1, a0); b0 = fmaf(w.x, m2, b0); }
        if (TB.mj[1][t]) { a1 = fmaf(w.y, m1, a1); b1 = fmaf(w.y, m2, b1); }
        if (TB.mj[2][t]) { a2 = fmaf(w.z, m1, a2); b2 = fmaf(w.z, m2, b2); }
        if (TB.mj[3][t]) { a3 = fmaf(w.w, m1, a3); b3 = fmaf(w.w, m2, b3); }
    }
    *reinterpret_cast<float4*>(out + (size_t)(i0 * OUTHW + j) * 4) =
        make_float4(a0, a1, a2, a3);
    if (i0 + 1 < OUTHW)
        *reinterpret_cast<float4*>(out + (size_t)((i0 + 1) * OUTHW + j) * 4) =
            make_float4(b0, b1, b2, b3);
}

extern "C" void kernel_launch(void* const* d_in, const int* in_sizes, int n_in,
                              void* d_out, int out_size, void* d_ws, size_t ws_size,
                              hipStream_t stream) {
    const float* x   = (const float*)d_in[0];   // [1,3,512,512] f32
    const float* wts = (const float*)d_in[1];   // [2,4] f32
    float* out = (float*)d_out;                 // [1,4,511,511] f32

    dim3 grid((OUTHW + 255) / 256, (OUTHW + 1) / 2);  // (2, 256)
    hipLaunchKernelGGL(quanv_fused, grid, dim3(256), 0, stream, x, wts, out);
}